// Round 1
// baseline (154.662 us; speedup 1.0000x reference)
//
#include <hip/hip_runtime.h>
#include <math.h>

#define EMB 64
#define ROWS 64          // memory rows (aug rows 1..64)
#define UNITS 1184
#define OUTN 1024
#define ZCOLS 4736       // 4*UNITS

__device__ __forceinline__ float stable_sigmoid(float x) {
    if (x >= 0.0f) return 1.0f / (1.0f + expf(-x));
    float e = expf(x);
    return e / (1.0f + e);
}

// One DSTEP substep of the potential ODE for channel value pc (other channel po).
__device__ __forceinline__ float pot_sub(float pc, float po) {
    // j=0: pre=inp=0             j=1: pre=p          j=2: pre=p reversed   j=3: pre=inf
    float t0 = 0.07915332f * stable_sigmoid(100.0f * (0.0f - 0.5f))        * (1.5931877f - pc);
    float t1 = 1.0334609f  * stable_sigmoid(100.0f * (pc - 0.07879465f))   * (1.4378392f - pc);
    float t2 = 1.3365093f  * stable_sigmoid(100.0f * (po - 0.06618887f))   * (0.0f - pc);
    float t3 = 0.4505964f  * 1.0f                                          * (0.0f - pc);
    return pc + (t0 + t1 + t2 + t3) * (1.5573331f / 2.0f);
}

__device__ __forceinline__ float pot_a7() {
    // pot starts [0,1]; 7 scan steps have updated it before step t=7 reads mem.
    float p0 = 0.0f, p1 = 1.0f;
    for (int t = 0; t < 7; ++t)
        for (int s = 0; s < 2; ++s) {
            float n0 = pot_sub(p0, p1);
            float n1 = pot_sub(p1, p0);
            p0 = n0; p1 = n1;
        }
    return p0;   // mem = pot[...,0]
}

// Kernel 1: batch-independent K/V for memory rows.
// kv[0      + l*128 + h*64 + k] = K(aug row l+1)
// kv[8192   + l*128 + h*64 + k] = V(aug row l+1)
__global__ __launch_bounds__(256)
void precompute_kv(const float* __restrict__ Wm, const float* __restrict__ bm,
                   const float* __restrict__ Wk, const float* __restrict__ bk,
                   const float* __restrict__ Wv, const float* __restrict__ bv,
                   float* __restrict__ kv) {
    __shared__ float s_m[EMB];
    __shared__ float aug[ROWS][EMB];
    const int tid = threadIdx.x;

    const float a = pot_a7();

    if (tid < EMB) {
        float s = 0.0f;
        for (int d = 0; d < 256; ++d) s += Wm[d * EMB + tid];
        s_m[tid] = a * s + bm[tid];        // emb_mem row (same for all 64 rows)
    }
    __syncthreads();

    for (int idx = tid; idx < ROWS * EMB; idx += blockDim.x) {
        const int l = idx >> 6, d = idx & 63;     // pos = l+1
        double expo = (double)(2 * (d >> 1)) / 64.0;
        double ang  = (double)(l + 1) / pow(10000.0, expo);
        float pe = (d & 1) ? (float)cos(ang) : (float)sin(ang);
        aug[l][d] = s_m[d] + pe;
    }
    __syncthreads();

    // 16384 outputs over 8 blocks
    const int base = blockIdx.x * 2048;
    for (int i = tid; i < 2048; i += blockDim.x) {
        const int idx = base + i;
        const int isv = idx >> 13;        // 0 = K, 1 = V
        const int r   = idx & 8191;
        const int l   = r >> 7;           // memory row
        const int t   = r & 127;          // h*64 + k
        const float* W  = isv ? Wv : Wk;
        const float* bb = isv ? bv : bk;
        float s = bb[t];
        #pragma unroll 8
        for (int d = 0; d < EMB; ++d) s += aug[l][d] * W[d * 128 + t];
        kv[idx] = s;
    }
}

// Kernel 2: per batch element (128 blocks): step t=7 attention + gated output.
__global__ __launch_bounds__(256)
void attend(const float* __restrict__ queries, const float* __restrict__ values,
            const float* __restrict__ Wi, const float* __restrict__ bi,
            const float* __restrict__ Wq, const float* __restrict__ bq,
            const float* __restrict__ Wk, const float* __restrict__ bk,
            const float* __restrict__ Wv, const float* __restrict__ bv,
            const float* __restrict__ Wo, const float* __restrict__ bo,
            const float* __restrict__ Wx, const float* __restrict__ bl,
            const float* __restrict__ kv, float* __restrict__ out) {
    const int b = blockIdx.x, tid = threadIdx.x;
    __shared__ float x[32], e[EMB], qv[128], k0[128], v0[128], att[2][65], ctx[128], o[EMB];

    if (tid < 16)      x[tid] = queries[b * 16 + tid];                      // queries[b/16, b%16, :]
    else if (tid < 32) x[tid] = values[(b >> 4) * 128 + 112 + (tid - 16)];  // values[b/16, 7, :]
    __syncthreads();

    if (tid < EMB) {
        float s = bi[tid] + ((tid & 1) ? 1.0f : 0.0f);   // + PE[0]: sin(0)=0 / cos(0)=1
        #pragma unroll 8
        for (int i = 0; i < 32; ++i) s += x[i] * Wi[i * EMB + tid];
        e[tid] = s;
    }
    __syncthreads();

    if (tid < 128) {
        float s = bq[tid];
        #pragma unroll 8
        for (int d = 0; d < EMB; ++d) s += e[d] * Wq[d * 128 + tid];
        qv[tid] = s;
        float sv = bv[tid];
        #pragma unroll 8
        for (int d = 0; d < EMB; ++d) sv += e[d] * Wv[d * 128 + tid];
        v0[tid] = sv;
    } else {
        const int t = tid - 128;
        float s = bk[t];
        #pragma unroll 8
        for (int d = 0; d < EMB; ++d) s += e[d] * Wk[d * 128 + t];
        k0[t] = s;
    }
    __syncthreads();

    if (tid < 130) {
        const int h = tid & 1, l = tid >> 1;     // l in 0..64
        const float* qh = &qv[h * 64];
        float s = 0.0f;
        if (l == 0) {
            #pragma unroll 8
            for (int d = 0; d < 64; ++d) s += qh[d] * k0[h * 64 + d];
        } else {
            const float* kr = &kv[(l - 1) * 128 + h * 64];
            #pragma unroll 8
            for (int d = 0; d < 64; ++d) s += qh[d] * kr[d];
        }
        att[h][l] = s * 0.125f;    // scale = 1/sqrt(64)
    }
    __syncthreads();

    if (tid < 2) {
        float m = -1e30f;
        for (int l = 0; l < 65; ++l) m = fmaxf(m, att[tid][l]);
        float sum = 0.0f;
        for (int l = 0; l < 65; ++l) { float ex = expf(att[tid][l] - m); att[tid][l] = ex; sum += ex; }
        float inv = 1.0f / sum;
        for (int l = 0; l < 65; ++l) att[tid][l] *= inv;
    }
    __syncthreads();

    if (tid < 128) {
        const int h = tid >> 6;
        float s = att[h][0] * v0[tid];
        const float* vm = &kv[8192 + tid];
        #pragma unroll 8
        for (int l = 0; l < 64; ++l) s += att[h][l + 1] * vm[l * 128];
        ctx[tid] = s;
    }
    __syncthreads();

    if (tid < 64) {
        float s = bo[tid];
        #pragma unroll 8
        for (int t = 0; t < 128; ++t) s += ctx[t] * Wo[t * 64 + tid];   // Wo[h,k,d] flat = (h*64+k)*64+d
        o[tid] = s;
    }
    __syncthreads();

    // z = o @ Wx + bl; need zi=z[j], zg=z[2368+j], zo=z[3552+j], j<1024 (zf dead)
    for (int j = tid; j < OUTN; j += blockDim.x) {
        float zi = bl[j], zg = bl[2 * UNITS + j], zo = bl[3 * UNITS + j];
        #pragma unroll 8
        for (int d = 0; d < EMB; ++d) {
            const float od = o[d];
            const float* row = &Wx[d * ZCOLS];
            zi += od * row[j];
            zg += od * row[2 * UNITS + j];
            zo += od * row[3 * UNITS + j];
        }
        const float c = stable_sigmoid(zi) * tanhf(zg);
        out[b * OUTN + j] = stable_sigmoid(zo) * tanhf(c);
    }
}

extern "C" void kernel_launch(void* const* d_in, const int* in_sizes, int n_in,
                              void* d_out, int out_size, void* d_ws, size_t ws_size,
                              hipStream_t stream) {
    const float* queries = (const float*)d_in[0];
    const float* values  = (const float*)d_in[1];
    const float* Wi = (const float*)d_in[2];
    const float* bi = (const float*)d_in[3];
    const float* Wm = (const float*)d_in[4];
    const float* bm = (const float*)d_in[5];
    const float* Wq = (const float*)d_in[6];
    const float* bq = (const float*)d_in[7];
    const float* Wk = (const float*)d_in[8];
    const float* bk = (const float*)d_in[9];
    const float* Wv = (const float*)d_in[10];
    const float* bv = (const float*)d_in[11];
    const float* Wo = (const float*)d_in[12];
    const float* bo = (const float*)d_in[13];
    const float* Wx = (const float*)d_in[14];
    const float* bl = (const float*)d_in[15];
    float* out = (float*)d_out;
    float* kv  = (float*)d_ws;    // 16384 floats = 64 KiB

    precompute_kv<<<8, 256, 0, stream>>>(Wm, bm, Wk, bk, Wv, bv, kv);
    attend<<<128, 256, 0, stream>>>(queries, values, Wi, bi, Wq, bq, Wk, bk,
                                    Wv, bv, Wo, bo, Wx, bl, kv, out);
}

// Round 2
// 122.382 us; speedup vs baseline: 1.2638x; 1.2638x over previous
//
#include <hip/hip_runtime.h>
#include <math.h>

#define EMB 64
#define ROWS 64          // memory rows (aug rows 1..64)
#define UNITS 1184
#define OUTN 1024
#define ZCOLS 4736       // 4*UNITS
#define KV_OFF 16384     // ws float offset where o[128][64] lives

__device__ __forceinline__ float stable_sigmoid(float x) {
    if (x >= 0.0f) return 1.0f / (1.0f + expf(-x));
    float e = expf(x);
    return e / (1.0f + e);
}

// One DSTEP substep of the potential ODE for channel value pc (other channel po).
__device__ __forceinline__ float pot_sub(float pc, float po) {
    float t0 = 0.07915332f * stable_sigmoid(100.0f * (0.0f - 0.5f))        * (1.5931877f - pc);
    float t1 = 1.0334609f  * stable_sigmoid(100.0f * (pc - 0.07879465f))   * (1.4378392f - pc);
    float t2 = 1.3365093f  * stable_sigmoid(100.0f * (po - 0.06618887f))   * (0.0f - pc);
    float t3 = 0.4505964f  * 1.0f                                          * (0.0f - pc);
    return pc + (t0 + t1 + t2 + t3) * (1.5573331f / 2.0f);
}

__device__ __forceinline__ float pot_a7() {
    float p0 = 0.0f, p1 = 1.0f;
    for (int t = 0; t < 7; ++t)
        for (int s = 0; s < 2; ++s) {
            float n0 = pot_sub(p0, p1);
            float n1 = pot_sub(p1, p0);
            p0 = n0; p1 = n1;
        }
    return p0;   // mem = pot[...,0]
}

// Kernel 1: batch-independent K/V for the 64 memory rows.
// kv[l*128 + h*64 + k] = K(row l+1);  kv[8192 + ...] = V(row l+1)
// 32 blocks x 256 threads, 512 outputs per block.
__global__ __launch_bounds__(256)
void precompute_kv(const float* __restrict__ Wm, const float* __restrict__ bm,
                   const float* __restrict__ Wk, const float* __restrict__ bk,
                   const float* __restrict__ Wv, const float* __restrict__ bv,
                   float* __restrict__ kv) {
    __shared__ float part[4][EMB];
    __shared__ float s_m[EMB];
    __shared__ float aug[ROWS][EMB];
    const int tid = threadIdx.x;

    // colsum(Wm): 256 threads = 4 row-groups x 64 cols
    {
        const int rg = tid >> 6, c = tid & 63;
        float s = 0.0f;
        #pragma unroll 8
        for (int r = 0; r < 64; ++r) s += Wm[(rg * 64 + r) * EMB + c];
        part[rg][c] = s;
    }
    __syncthreads();
    if (tid < EMB) {
        const float a = pot_a7();
        s_m[tid] = a * (part[0][tid] + part[1][tid] + part[2][tid] + part[3][tid]) + bm[tid];
    }
    __syncthreads();

    // aug rows (fp32 PE; err ~1e-6, threshold 1.1e-3)
    for (int idx = tid; idx < ROWS * EMB; idx += 256) {
        const int l = idx >> 6, d = idx & 63;            // pos = l+1
        const float inv = exp2f(-(float)(2 * (d >> 1)) * (13.287712379549449f / 64.0f));
        const float ang = (float)(l + 1) * inv;
        const float pe  = (d & 1) ? cosf(ang) : sinf(ang);
        aug[l][d] = s_m[d] + pe;
    }
    __syncthreads();

    const int base = blockIdx.x * 512;
    for (int i = tid; i < 512; i += 256) {
        const int idx = base + i;
        const int isv = idx >> 13;        // 0 = K, 1 = V
        const int r   = idx & 8191;
        const int l   = r >> 7;
        const int t   = r & 127;          // h*64+k  (consecutive threads -> coalesced)
        const float* W  = isv ? Wv : Wk;
        const float* bb = isv ? bv : bk;
        float s = bb[t];
        #pragma unroll 16
        for (int d = 0; d < EMB; ++d) s += aug[l][d] * W[d * 128 + t];
        kv[idx] = s;
    }
}

// Kernel 2: per batch (128 blocks): step t=7 attention -> o[b][64] into ws.
__global__ __launch_bounds__(256)
void attend_o(const float* __restrict__ queries, const float* __restrict__ values,
              const float* __restrict__ Wi, const float* __restrict__ bi,
              const float* __restrict__ Wq, const float* __restrict__ bq,
              const float* __restrict__ Wk, const float* __restrict__ bk,
              const float* __restrict__ Wv, const float* __restrict__ bv,
              const float* __restrict__ Wo, const float* __restrict__ bo,
              const float* __restrict__ kv, float* __restrict__ o_out) {
    const int b = blockIdx.x, tid = threadIdx.x;
    __shared__ float x[32], e[EMB], qv[128], k0[128], v0[128], att[2][65], ctx[128];

    if (tid < 16)      x[tid] = queries[b * 16 + tid];
    else if (tid < 32) x[tid] = values[(b >> 4) * 128 + 112 + (tid - 16)];  // values[b/16, 7, :]
    __syncthreads();

    if (tid < EMB) {
        float s = bi[tid] + ((tid & 1) ? 1.0f : 0.0f);   // + PE[0]
        #pragma unroll 8
        for (int i = 0; i < 32; ++i) s += x[i] * Wi[i * EMB + tid];
        e[tid] = s;
    }
    __syncthreads();

    if (tid < 128) {
        float s = bq[tid];
        #pragma unroll 8
        for (int d = 0; d < EMB; ++d) s += e[d] * Wq[d * 128 + tid];
        qv[tid] = s;
        float sv = bv[tid];
        #pragma unroll 8
        for (int d = 0; d < EMB; ++d) sv += e[d] * Wv[d * 128 + tid];
        v0[tid] = sv;
    } else {
        const int t = tid - 128;
        float s = bk[t];
        #pragma unroll 8
        for (int d = 0; d < EMB; ++d) s += e[d] * Wk[d * 128 + t];
        k0[t] = s;
    }
    __syncthreads();

    if (tid < 130) {
        const int h = tid & 1, l = tid >> 1;     // l in 0..64
        const float* qh = &qv[h * 64];
        float s = 0.0f;
        if (l == 0) {
            #pragma unroll 8
            for (int d = 0; d < 64; ++d) s += qh[d] * k0[h * 64 + d];
        } else {
            const float* kr = &kv[(l - 1) * 128 + h * 64];
            #pragma unroll 8
            for (int d = 0; d < 64; ++d) s += qh[d] * kr[d];
        }
        att[h][l] = s * 0.125f;
    }
    __syncthreads();

    if (tid < 2) {
        float m = -1e30f;
        for (int l = 0; l < 65; ++l) m = fmaxf(m, att[tid][l]);
        float sum = 0.0f;
        for (int l = 0; l < 65; ++l) { float ex = expf(att[tid][l] - m); att[tid][l] = ex; sum += ex; }
        float inv = 1.0f / sum;
        for (int l = 0; l < 65; ++l) att[tid][l] *= inv;
    }
    __syncthreads();

    if (tid < 128) {
        const int h = tid >> 6;
        float s = att[h][0] * v0[tid];
        const float* vm = &kv[8192 + tid];
        #pragma unroll 8
        for (int l = 0; l < 64; ++l) s += att[h][l + 1] * vm[l * 128];
        ctx[tid] = s;
    }
    __syncthreads();

    if (tid < 64) {
        float s = bo[tid];
        #pragma unroll 16
        for (int t = 0; t < 128; ++t) s += ctx[t] * Wo[t * 64 + tid];
        o_out[b * 64 + tid] = s;
    }
}

// Kernel 3: out[b][j] from o[b][:] and Wx columns {j, 2368+j, 3552+j}.
// 512 blocks (b*4+quarter) x 256 threads, one j per thread. 8 waves/CU.
__global__ __launch_bounds__(256)
void out_gemm(const float* __restrict__ Wx, const float* __restrict__ bl,
              const float* __restrict__ o_in, float* __restrict__ out) {
    const int b = blockIdx.x >> 2;
    const int j = ((blockIdx.x & 3) << 8) | threadIdx.x;
    __shared__ float o[EMB];
    if (threadIdx.x < EMB) o[threadIdx.x] = o_in[b * EMB + threadIdx.x];
    __syncthreads();

    float zi = bl[j], zg = bl[2 * UNITS + j], zo = bl[3 * UNITS + j];
    const float* col = Wx + j;
    #pragma unroll 16
    for (int d = 0; d < EMB; ++d) {
        const float od = o[d];
        const float* row = col + d * ZCOLS;
        zi += od * row[0];
        zg += od * row[2 * UNITS];
        zo += od * row[3 * UNITS];
    }
    const float c = stable_sigmoid(zi) * tanhf(zg);
    out[b * OUTN + j] = stable_sigmoid(zo) * tanhf(c);
}

extern "C" void kernel_launch(void* const* d_in, const int* in_sizes, int n_in,
                              void* d_out, int out_size, void* d_ws, size_t ws_size,
                              hipStream_t stream) {
    const float* queries = (const float*)d_in[0];
    const float* values  = (const float*)d_in[1];
    const float* Wi = (const float*)d_in[2];
    const float* bi = (const float*)d_in[3];
    const float* Wm = (const float*)d_in[4];
    const float* bm = (const float*)d_in[5];
    const float* Wq = (const float*)d_in[6];
    const float* bq = (const float*)d_in[7];
    const float* Wk = (const float*)d_in[8];
    const float* bk = (const float*)d_in[9];
    const float* Wv = (const float*)d_in[10];
    const float* bv = (const float*)d_in[11];
    const float* Wo = (const float*)d_in[12];
    const float* bo = (const float*)d_in[13];
    const float* Wx = (const float*)d_in[14];
    const float* bl = (const float*)d_in[15];
    float* out = (float*)d_out;
    float* kv  = (float*)d_ws;            // 16384 floats
    float* o_b = (float*)d_ws + KV_OFF;   // 128*64 floats

    precompute_kv<<<32, 256, 0, stream>>>(Wm, bm, Wk, bk, Wv, bv, kv);
    attend_o<<<128, 256, 0, stream>>>(queries, values, Wi, bi, Wq, bq, Wk, bk,
                                      Wv, bv, Wo, bo, kv, o_b);
    out_gemm<<<512, 256, 0, stream>>>(Wx, bl, o_b, out);
}

// Round 3
// 118.550 us; speedup vs baseline: 1.3046x; 1.0323x over previous
//
#include <hip/hip_runtime.h>
#include <math.h>

#define EMB 64
#define ROWS 64          // memory rows (aug rows 1..64)
#define UNITS 1184
#define OUTN 1024
#define ZCOLS 4736       // 4*UNITS

__device__ __forceinline__ float stable_sigmoid(float x) {
    if (x >= 0.0f) return 1.0f / (1.0f + expf(-x));
    float e = expf(x);
    return e / (1.0f + e);
}

// One DSTEP substep of the potential ODE for channel value pc (other channel po).
__device__ __forceinline__ float pot_sub(float pc, float po) {
    float t0 = 0.07915332f * stable_sigmoid(100.0f * (0.0f - 0.5f))        * (1.5931877f - pc);
    float t1 = 1.0334609f  * stable_sigmoid(100.0f * (pc - 0.07879465f))   * (1.4378392f - pc);
    float t2 = 1.3365093f  * stable_sigmoid(100.0f * (po - 0.06618887f))   * (0.0f - pc);
    float t3 = 0.4505964f  * 1.0f                                          * (0.0f - pc);
    return pc + (t0 + t1 + t2 + t3) * (1.5573331f / 2.0f);
}

__device__ __forceinline__ float pot_a7() {
    float p0 = 0.0f, p1 = 1.0f;
    for (int t = 0; t < 7; ++t)
        for (int s = 0; s < 2; ++s) {
            float n0 = pot_sub(p0, p1);
            float n1 = pot_sub(p1, p0);
            p0 = n0; p1 = n1;
        }
    return p0;   // mem = pot[...,0]
}

// Kernel 1: batch-independent K/V for the 64 memory rows.
// kv[l*128 + h*64 + k] = K(row l+1);  kv[8192 + ...] = V(row l+1)
// 64 blocks x 256 threads, exactly 1 output per thread.
__global__ __launch_bounds__(256)
void precompute_kv(const float* __restrict__ Wm, const float* __restrict__ bm,
                   const float* __restrict__ Wk, const float* __restrict__ bk,
                   const float* __restrict__ Wv, const float* __restrict__ bv,
                   float* __restrict__ kv) {
    __shared__ float part[4][EMB];
    __shared__ float s_m[EMB];
    __shared__ float aug[ROWS][EMB];
    const int tid = threadIdx.x;

    // colsum(Wm): 4 row-groups x 64 cols (redundant per block; L2-resident)
    {
        const int rg = tid >> 6, c = tid & 63;
        float s = 0.0f;
        #pragma unroll 8
        for (int r = 0; r < 64; ++r) s += Wm[(rg * 64 + r) * EMB + c];
        part[rg][c] = s;
    }
    __syncthreads();
    if (tid < EMB) {
        const float a = pot_a7();
        s_m[tid] = a * (part[0][tid] + part[1][tid] + part[2][tid] + part[3][tid]) + bm[tid];
    }
    __syncthreads();

    // aug rows (fp32 PE; err ~1e-6, threshold 1.1e-3)
    for (int idx = tid; idx < ROWS * EMB; idx += 256) {
        const int l = idx >> 6, d = idx & 63;            // pos = l+1
        const float inv = exp2f(-(float)(2 * (d >> 1)) * (13.287712379549449f / 64.0f));
        const float ang = (float)(l + 1) * inv;
        const float pe  = (d & 1) ? cosf(ang) : sinf(ang);
        aug[l][d] = s_m[d] + pe;
    }
    __syncthreads();

    const int idx = blockIdx.x * 256 + tid;
    const int isv = idx >> 13;        // 0 = K, 1 = V
    const int r   = idx & 8191;
    const int l   = r >> 7;
    const int t   = r & 127;          // h*64+k  (consecutive threads -> coalesced)
    const float* W  = isv ? Wv : Wk;
    const float* bb = isv ? bv : bk;
    float s = bb[t];
    #pragma unroll 16
    for (int d = 0; d < EMB; ++d) s += aug[l][d] * W[d * 128 + t];
    kv[idx] = s;
}

// Kernel 2 (fused): 512 blocks = (b, quarter). Each block redundantly runs the
// cheap attention chain for batch b (parallel redundancy is free), then computes
// its 256 output columns j directly from LDS o.
__global__ __launch_bounds__(256)
void attend_out(const float* __restrict__ queries, const float* __restrict__ values,
                const float* __restrict__ Wi, const float* __restrict__ bi,
                const float* __restrict__ Wq, const float* __restrict__ bq,
                const float* __restrict__ Wk, const float* __restrict__ bk,
                const float* __restrict__ Wv, const float* __restrict__ bv,
                const float* __restrict__ Wo, const float* __restrict__ bo,
                const float* __restrict__ Wx, const float* __restrict__ bl,
                const float* __restrict__ kv, float* __restrict__ out) {
    const int b = blockIdx.x >> 2, tid = threadIdx.x;
    __shared__ float x[32], e[EMB], qv[128], k0[128], v0[128], att[2][65], ctx[128], o[EMB];

    if (tid < 16)      x[tid] = queries[b * 16 + tid];
    else if (tid < 32) x[tid] = values[(b >> 4) * 128 + 112 + (tid - 16)];  // values[b/16, 7, :]
    __syncthreads();

    if (tid < EMB) {
        float s = bi[tid] + ((tid & 1) ? 1.0f : 0.0f);   // + PE[0]: sin(0)=0 / cos(0)=1
        #pragma unroll 8
        for (int i = 0; i < 32; ++i) s += x[i] * Wi[i * EMB + tid];
        e[tid] = s;
    }
    __syncthreads();

    if (tid < 128) {
        float s = bq[tid];
        #pragma unroll 8
        for (int d = 0; d < EMB; ++d) s += e[d] * Wq[d * 128 + tid];
        qv[tid] = s;
        float sv = bv[tid];
        #pragma unroll 8
        for (int d = 0; d < EMB; ++d) sv += e[d] * Wv[d * 128 + tid];
        v0[tid] = sv;
    } else {
        const int t = tid - 128;
        float s = bk[t];
        #pragma unroll 8
        for (int d = 0; d < EMB; ++d) s += e[d] * Wk[d * 128 + t];
        k0[t] = s;
    }
    __syncthreads();

    if (tid < 130) {
        const int h = tid & 1, l = tid >> 1;     // l in 0..64
        const float* qh = &qv[h * 64];
        float s = 0.0f;
        if (l == 0) {
            #pragma unroll 8
            for (int d = 0; d < 64; ++d) s += qh[d] * k0[h * 64 + d];
        } else {
            const float* kr = &kv[(l - 1) * 128 + h * 64];
            #pragma unroll 8
            for (int d = 0; d < 64; ++d) s += qh[d] * kr[d];
        }
        att[h][l] = s * 0.125f;    // scale = 1/sqrt(64)
    }
    __syncthreads();

    if (tid < 2) {
        float m = -1e30f;
        for (int l = 0; l < 65; ++l) m = fmaxf(m, att[tid][l]);
        float sum = 0.0f;
        for (int l = 0; l < 65; ++l) { float ex = expf(att[tid][l] - m); att[tid][l] = ex; sum += ex; }
        float inv = 1.0f / sum;
        for (int l = 0; l < 65; ++l) att[tid][l] *= inv;
    }
    __syncthreads();

    if (tid < 128) {
        const int h = tid >> 6;
        float s = att[h][0] * v0[tid];
        const float* vm = &kv[8192 + tid];
        #pragma unroll 8
        for (int l = 0; l < 64; ++l) s += att[h][l + 1] * vm[l * 128];
        ctx[tid] = s;
    }
    __syncthreads();

    if (tid < 64) {
        float s = bo[tid];
        #pragma unroll 16
        for (int t = 0; t < 128; ++t) s += ctx[t] * Wo[t * 64 + tid];   // Wo[h,k,d] flat
        o[tid] = s;
    }
    __syncthreads();

    // out phase: this block's 256 j's; z cols {j, 2368+j, 3552+j}; zf dead.
    const int j = ((blockIdx.x & 3) << 8) | tid;
    float zi = bl[j], zg = bl[2 * UNITS + j], zo = bl[3 * UNITS + j];
    const float* col = Wx + j;
    #pragma unroll 16
    for (int d = 0; d < EMB; ++d) {
        const float od = o[d];
        const float* row = col + d * ZCOLS;
        zi += od * row[0];
        zg += od * row[2 * UNITS];
        zo += od * row[3 * UNITS];
    }
    const float c = stable_sigmoid(zi) * tanhf(zg);
    out[b * OUTN + j] = stable_sigmoid(zo) * tanhf(c);
}

extern "C" void kernel_launch(void* const* d_in, const int* in_sizes, int n_in,
                              void* d_out, int out_size, void* d_ws, size_t ws_size,
                              hipStream_t stream) {
    const float* queries = (const float*)d_in[0];
    const float* values  = (const float*)d_in[1];
    const float* Wi = (const float*)d_in[2];
    const float* bi = (const float*)d_in[3];
    const float* Wm = (const float*)d_in[4];
    const float* bm = (const float*)d_in[5];
    const float* Wq = (const float*)d_in[6];
    const float* bq = (const float*)d_in[7];
    const float* Wk = (const float*)d_in[8];
    const float* bk = (const float*)d_in[9];
    const float* Wv = (const float*)d_in[10];
    const float* bv = (const float*)d_in[11];
    const float* Wo = (const float*)d_in[12];
    const float* bo = (const float*)d_in[13];
    const float* Wx = (const float*)d_in[14];
    const float* bl = (const float*)d_in[15];
    float* out = (float*)d_out;
    float* kv  = (float*)d_ws;            // 16384 floats = 64 KiB

    precompute_kv<<<64, 256, 0, stream>>>(Wm, bm, Wk, bk, Wv, bv, kv);
    attend_out<<<512, 256, 0, stream>>>(queries, values, Wi, bi, Wq, bq, Wk, bk,
                                        Wv, bv, Wo, bo, Wx, bl, kv, out);
}